// Round 1
// baseline (3215.044 us; speedup 1.0000x reference)
//
#include <hip/hip_runtime.h>

// SubResidualGeoLossl: two gathered sparse 3x3x3 convs over 400k voxels.
//   h   = relu( sum_k gather(concat(x,y), nbr[k]) @ w1[k] + b1 )   K=128
//   out = clip( sum_k gather(h,           nbr[k]) @ w2[k] + b2 , -2, 2)  K=64
// Sentinel nbr value == NPTS means "no neighbor" -> zero row.

#define NPTS 400000
#define TAPS 27
#define TM   64     // points per block tile

// Block: 256 threads as 16(point-groups) x 16(channel-groups); each thread owns
// a 4x4 (points x out-channels) accumulator. Per tap, features are staged in
// 64-channel chunks (conv1: chunk0 = x_feat, chunk1 = y_feat -> concat is free).
template<int NCHUNK, bool RELU, bool CLIP>
__global__ __launch_bounds__(256) void spconv_kernel(
    const float* __restrict__ f0, const float* __restrict__ f1,
    const float* __restrict__ w, const float* __restrict__ bias,
    const int* __restrict__ nbr, float* __restrict__ out)
{
    // fs stride 68 dwords = 272 B: 16B-aligned for ds_read_b128, and the four
    // broadcast row-reads of the micro-kernel land on 2 bank-groups (2-way = free).
    __shared__ float fs[TM][68];
    __shared__ float wls[64][64];
    __shared__ int   idx_s[TM];

    const int tid = threadIdx.x;
    const int n0  = blockIdx.x * TM;
    const int tr  = tid >> 4;   // 0..15 -> points 4*tr .. 4*tr+3
    const int tc  = tid & 15;   // 0..15 -> channels 4*tc .. 4*tc+3

    float acc[4][4];
    {
        float bv[4];
        *(float4*)bv = *(const float4*)&bias[4 * tc];
        #pragma unroll
        for (int i = 0; i < 4; ++i)
            #pragma unroll
            for (int j = 0; j < 4; ++j)
                acc[i][j] = bv[j];
    }

    const int scol  = tid & 15;  // staging float4 column
    const int srow0 = tid >> 4;  // staging row base

    for (int k = 0; k < TAPS; ++k) {
        if (tid < TM) idx_s[tid] = nbr[k * NPTS + n0 + tid];
        #pragma unroll
        for (int ch = 0; ch < NCHUNK; ++ch) {
            __syncthreads();   // previous compute done (also publishes idx_s on ch==0)
            // ---- stage gathered feature rows (64 rows x 64 ch chunk) ----
            const float* fsrc = (NCHUNK == 2 && ch == 1) ? f1 : f0;
            #pragma unroll
            for (int i = 0; i < 4; ++i) {
                const int r  = srow0 + 16 * i;
                const int gi = idx_s[r];
                float v[4] = {0.f, 0.f, 0.f, 0.f};
                if (gi < NPTS)
                    *(float4*)v = *(const float4*)&fsrc[(size_t)gi * 64 + 4 * scol];
                *(float4*)&fs[r][4 * scol] = *(float4*)v;
            }
            // ---- stage weight slab w[k, ch*64 : ch*64+64, :] (64x64) ----
            const float* wsrc = w + (size_t)(k * NCHUNK + ch) * 64 * 64;
            #pragma unroll
            for (int i = 0; i < 4; ++i) {
                const int cc = srow0 + 16 * i;
                *(float4*)&wls[cc][4 * scol] = *(const float4*)&wsrc[cc * 64 + 4 * scol];
            }
            __syncthreads();
            // ---- 4x4 register-tile GEMM over the 64-channel chunk ----
            #pragma unroll 4
            for (int c4 = 0; c4 < 64; c4 += 4) {
                float fv[4][4], wv[4][4];
                #pragma unroll
                for (int i = 0; i < 4; ++i)
                    *(float4*)fv[i] = *(const float4*)&fs[4 * tr + i][c4];
                #pragma unroll
                for (int q = 0; q < 4; ++q)
                    *(float4*)wv[q] = *(const float4*)&wls[c4 + q][4 * tc];
                #pragma unroll
                for (int q = 0; q < 4; ++q)
                    #pragma unroll
                    for (int i = 0; i < 4; ++i)
                        #pragma unroll
                        for (int j = 0; j < 4; ++j)
                            acc[i][j] += fv[i][q] * wv[q][j];
            }
        }
    }

    // ---- epilogue: bias already folded in; act + store ----
    #pragma unroll
    for (int i = 0; i < 4; ++i) {
        float v[4];
        #pragma unroll
        for (int j = 0; j < 4; ++j) {
            float xv = acc[i][j];
            if (RELU) xv = fmaxf(xv, 0.f);
            if (CLIP) xv = fminf(fmaxf(xv, -2.f), 2.f);
            v[j] = xv;
        }
        const int n = n0 + 4 * tr + i;
        *(float4*)&out[(size_t)n * 64 + 4 * tc] = *(float4*)v;
    }
}

extern "C" void kernel_launch(void* const* d_in, const int* in_sizes, int n_in,
                              void* d_out, int out_size, void* d_ws, size_t ws_size,
                              hipStream_t stream) {
    const float* x  = (const float*)d_in[0];
    const float* y  = (const float*)d_in[1];
    const float* w1 = (const float*)d_in[2];
    const float* b1 = (const float*)d_in[3];
    const float* w2 = (const float*)d_in[4];
    const float* b2 = (const float*)d_in[5];
    const int*   nbr = (const int*)d_in[6];
    float* out = (float*)d_out;
    float* h   = (float*)d_ws;   // [NPTS, 64] intermediate, fully overwritten

    dim3 grid(NPTS / TM), block(256);
    // conv1 + relu  (K = 128 as two 64-chunks: x then y)
    spconv_kernel<2, true, false><<<grid, block, 0, stream>>>(x, y, w1, b1, nbr, h);
    // conv2 + clip
    spconv_kernel<1, false, true><<<grid, block, 0, stream>>>(h, h, w2, b2, nbr, out);
}

// Round 2
// 754.216 us; speedup vs baseline: 4.2628x; 4.2628x over previous
//
#include <hip/hip_runtime.h>
#include <stdint.h>

// SubResidualGeoLossl on MI355X — MFMA bf16 hi/lo-split implementation.
//   h   = relu( sum_k gather(concat(x,y), nbr[k]) @ w1[k] + b1 )   K=128
//   out = clip( sum_k gather(h,           nbr[k]) @ w2[k] + b2 , -2, 2)  K=64
// fp32 emulated as bf16_hi + bf16_lo, 3-term MFMA (hh + lh + hl).

#define NPTS 400000
#define TAPS 27

typedef __attribute__((ext_vector_type(8))) short bf16x8;  // 8 bf16 = 4 VGPRs
typedef __attribute__((ext_vector_type(4))) float f32x4;

#define MFMA(a, b, c) __builtin_amdgcn_mfma_f32_16x16x32_bf16(a, b, c, 0, 0, 0)

// ---- scratch layout (bytes) ----
// h2:     [NPTS+1][128] bf16, row = hi[64] | lo[64]; row NPTS is zeros (sentinel)
// w1t_*:  [27][64 col][128 k] bf16 (transposed + split weights, conv1)
// w2t_*:  [27][64 col][64 k]  bf16 (conv2)
#define H2_BYTES   ((size_t)(NPTS + 1) * 256)
#define W1T_SZ     ((size_t)TAPS * 64 * 128 * 2)
#define W2T_SZ     ((size_t)TAPS * 64 * 64 * 2)
#define W1T_HI_OFF (H2_BYTES)
#define W1T_LO_OFF (W1T_HI_OFF + W1T_SZ)
#define W2T_HI_OFF (W1T_LO_OFF + W1T_SZ)
#define W2T_LO_OFF (W2T_HI_OFF + W2T_SZ)

__device__ inline uint16_t bf_rne(float f) {
    uint32_t u = __float_as_uint(f);
    return (uint16_t)((u + 0x7FFFu + ((u >> 16) & 1u)) >> 16);
}

// ---- prep: transpose+split weights to bf16 hi/lo; zero h2 sentinel row ----
__global__ __launch_bounds__(256) void prep_weights(
    const float* __restrict__ w1, const float* __restrict__ w2,
    uint16_t* __restrict__ w1t_hi, uint16_t* __restrict__ w1t_lo,
    uint16_t* __restrict__ w2t_hi, uint16_t* __restrict__ w2t_lo,
    uint16_t* __restrict__ h2)
{
    const int gid = blockIdx.x * 256 + threadIdx.x;
    const int n1 = TAPS * 64 * 128;   // 221184
    const int n2 = TAPS * 64 * 64;    // 110592
    if (gid < n1) {
        int k = gid & 127, col = (gid >> 7) & 63, tap = gid >> 13;
        float f = w1[((size_t)tap * 128 + k) * 64 + col];
        uint16_t hi = bf_rne(f);
        float r = f - __uint_as_float((uint32_t)hi << 16);
        w1t_hi[gid] = hi;
        w1t_lo[gid] = bf_rne(r);
    } else if (gid < n1 + n2) {
        int g = gid - n1;
        int k = g & 63, col = (g >> 6) & 63, tap = g >> 12;
        float f = w2[((size_t)tap * 64 + k) * 64 + col];
        uint16_t hi = bf_rne(f);
        float r = f - __uint_as_float((uint32_t)hi << 16);
        w2t_hi[g] = hi;
        w2t_lo[g] = bf_rne(r);
    } else if (gid < n1 + n2 + 128) {
        h2[(size_t)NPTS * 128 + (gid - n1 - n2)] = 0;  // sentinel zero row
    }
}

// truncation split of 8 f32 -> bf16 hi + lo (exact residual; bias cancels
// through random-sign weights, per-product rel err ~2^-16)
__device__ inline void split_trunc8(f32x4 v0, f32x4 v1, bf16x8& hi, bf16x8& lo) {
    float f[8];
    *(f32x4*)f = v0; *(f32x4*)(f + 4) = v1;
    short h[8], l[8];
#pragma unroll
    for (int j = 0; j < 8; ++j) {
        uint32_t u = __float_as_uint(f[j]);
        h[j] = (short)(u >> 16);
        float r = f[j] - __uint_as_float(u & 0xFFFF0000u);
        l[j] = (short)(__float_as_uint(r) >> 16);
    }
    hi = *(bf16x8*)h; lo = *(bf16x8*)l;
}

// ---- conv1: K=128 (x|y), A = f32 gather + on-the-fly split; out = h2 bf16 hi/lo ----
__global__ __launch_bounds__(256, 2) void conv1_kernel(
    const float* __restrict__ xf, const float* __restrict__ yf,
    const uint16_t* __restrict__ w1t_hi, const uint16_t* __restrict__ w1t_lo,
    const float* __restrict__ b1, const int* __restrict__ nbr,
    uint16_t* __restrict__ h2)
{
    __shared__ char wsh[16384];   // Wt_hi[64][128] bf16, XOR-swizzled
    __shared__ char wsl[16384];

    const int tid = threadIdx.x;
    const int wv = tid >> 6, ln = tid & 63;
    const int g4 = ln >> 4, c = ln & 15;
    const int base = blockIdx.x * 128 + wv * 32;
    const int swz = (c & 7) << 4;

    float bv[4];
#pragma unroll
    for (int nf = 0; nf < 4; ++nf) bv[nf] = b1[16 * nf + c];
    f32x4 acc[2][4];
#pragma unroll
    for (int mi = 0; mi < 2; ++mi)
#pragma unroll
        for (int nf = 0; nf < 4; ++nf)
            acc[mi][nf] = (f32x4){bv[nf], bv[nf], bv[nf], bv[nf]};

    for (int tap = 0; tap < TAPS; ++tap) {
        __syncthreads();  // prior tap's LDS reads done
        // stage W[tap] (16KB hi + 16KB lo) with XOR swizzle, reg-staged
        {
            const char* srcH = (const char*)w1t_hi + (size_t)tap * 16384;
            const char* srcL = (const char*)w1t_lo + (size_t)tap * 16384;
#pragma unroll
            for (int i = 0; i < 4; ++i) {
                int g = tid + 256 * i;           // 1024 16B chunks
                int byte = g << 4;
                int dst = byte ^ (((byte >> 8) & 7) << 4);
                *(bf16x8*)(wsh + dst) = *(const bf16x8*)(srcH + byte);
                *(bf16x8*)(wsl + dst) = *(const bf16x8*)(srcL + byte);
            }
        }
        // gather A rows + split to bf16 hi/lo (overlaps W staging latency)
        bf16x8 ah[2][4], al[2][4];
#pragma unroll
        for (int mi = 0; mi < 2; ++mi) {
            const int gi = nbr[tap * NPTS + base + mi * 16 + c];
            const bool valid = gi < NPTS;
            const float* rowx = xf + (size_t)gi * 64;
            const float* rowy = yf + (size_t)gi * 64;
#pragma unroll
            for (int kf = 0; kf < 4; ++kf) {
                const float* s = (kf < 2 ? rowx : rowy) + ((kf & 1) << 5) + (g4 << 3);
                f32x4 v0 = {0.f, 0.f, 0.f, 0.f}, v1 = {0.f, 0.f, 0.f, 0.f};
                if (valid) { v0 = *(const f32x4*)s; v1 = *(const f32x4*)(s + 4); }
                split_trunc8(v0, v1, ah[mi][kf], al[mi][kf]);
            }
        }
        __syncthreads();  // W visible
#pragma unroll
        for (int kf = 0; kf < 4; ++kf)
#pragma unroll
            for (int nf = 0; nf < 4; ++nf) {
                int byte = ((16 * nf + c) << 8) + (kf << 6) + (g4 << 4);
                int addr = byte ^ swz;
                bf16x8 bh = *(const bf16x8*)(wsh + addr);
                bf16x8 bl = *(const bf16x8*)(wsl + addr);
#pragma unroll
                for (int mi = 0; mi < 2; ++mi) {
                    acc[mi][nf] = MFMA(ah[mi][kf], bh, acc[mi][nf]);
                    acc[mi][nf] = MFMA(al[mi][kf], bh, acc[mi][nf]);
                    acc[mi][nf] = MFMA(ah[mi][kf], bl, acc[mi][nf]);
                }
            }
    }

    // epilogue: relu, split to bf16 hi/lo, store h2 rows
#pragma unroll
    for (int mi = 0; mi < 2; ++mi)
#pragma unroll
        for (int nf = 0; nf < 4; ++nf) {
#pragma unroll
            for (int r = 0; r < 4; ++r) {
                float h = fmaxf(acc[mi][nf][r], 0.f);
                uint32_t u = __float_as_uint(h);
                uint16_t hi = (uint16_t)(u >> 16);
                float rr = h - __uint_as_float(u & 0xFFFF0000u);
                uint16_t lo = (uint16_t)(__float_as_uint(rr) >> 16);
                const int pt = base + mi * 16 + (g4 << 2) + r;
                h2[(size_t)pt * 128 + 16 * nf + c] = hi;
                h2[(size_t)pt * 128 + 64 + 16 * nf + c] = lo;
            }
        }
}

// ---- conv2: K=64, A = h2 (bf16 hi/lo precomputed, zero sentinel row) ----
__global__ __launch_bounds__(256, 2) void conv2_kernel(
    const uint16_t* __restrict__ h2,
    const uint16_t* __restrict__ w2t_hi, const uint16_t* __restrict__ w2t_lo,
    const float* __restrict__ b2, const int* __restrict__ nbr,
    float* __restrict__ out)
{
    __shared__ char wsh[8192];   // Wt2_hi[64][64] bf16, XOR-swizzled
    __shared__ char wsl[8192];

    const int tid = threadIdx.x;
    const int wv = tid >> 6, ln = tid & 63;
    const int g4 = ln >> 4, c = ln & 15;
    const int base = blockIdx.x * 128 + wv * 32;
    const int swz = (c & 7) << 4;

    float bv[4];
#pragma unroll
    for (int nf = 0; nf < 4; ++nf) bv[nf] = b2[16 * nf + c];
    f32x4 acc[2][4];
#pragma unroll
    for (int mi = 0; mi < 2; ++mi)
#pragma unroll
        for (int nf = 0; nf < 4; ++nf)
            acc[mi][nf] = (f32x4){bv[nf], bv[nf], bv[nf], bv[nf]};

    for (int tap = 0; tap < TAPS; ++tap) {
        __syncthreads();
        {
            const char* srcH = (const char*)w2t_hi + (size_t)tap * 8192;
            const char* srcL = (const char*)w2t_lo + (size_t)tap * 8192;
#pragma unroll
            for (int i = 0; i < 2; ++i) {
                int g = tid + 256 * i;           // 512 16B chunks
                int byte = g << 4;
                int dst = byte ^ (((byte >> 7) & 7) << 4);
                *(bf16x8*)(wsh + dst) = *(const bf16x8*)(srcH + byte);
                *(bf16x8*)(wsl + dst) = *(const bf16x8*)(srcL + byte);
            }
        }
        bf16x8 ah[2][2], al[2][2];
#pragma unroll
        for (int mi = 0; mi < 2; ++mi) {
            const int gi = nbr[tap * NPTS + base + mi * 16 + c];
            const char* hrow = (const char*)h2 + (size_t)gi * 256;  // sentinel row = zeros
#pragma unroll
            for (int kf = 0; kf < 2; ++kf) {
                ah[mi][kf] = *(const bf16x8*)(hrow + (kf << 6) + (g4 << 4));
                al[mi][kf] = *(const bf16x8*)(hrow + 128 + (kf << 6) + (g4 << 4));
            }
        }
        __syncthreads();
#pragma unroll
        for (int kf = 0; kf < 2; ++kf)
#pragma unroll
            for (int nf = 0; nf < 4; ++nf) {
                int byte = ((16 * nf + c) << 7) + (kf << 6) + (g4 << 4);
                int addr = byte ^ swz;
                bf16x8 bh = *(const bf16x8*)(wsh + addr);
                bf16x8 bl = *(const bf16x8*)(wsl + addr);
#pragma unroll
                for (int mi = 0; mi < 2; ++mi) {
                    acc[mi][nf] = MFMA(ah[mi][kf], bh, acc[mi][nf]);
                    acc[mi][nf] = MFMA(al[mi][kf], bh, acc[mi][nf]);
                    acc[mi][nf] = MFMA(ah[mi][kf], bl, acc[mi][nf]);
                }
            }
    }

#pragma unroll
    for (int mi = 0; mi < 2; ++mi)
#pragma unroll
        for (int nf = 0; nf < 4; ++nf)
#pragma unroll
            for (int r = 0; r < 4; ++r) {
                float v = fminf(fmaxf(acc[mi][nf][r], -2.f), 2.f);
                const int pt = base + mi * 16 + (g4 << 2) + r;
                out[(size_t)pt * 64 + 16 * nf + c] = v;
            }
}

extern "C" void kernel_launch(void* const* d_in, const int* in_sizes, int n_in,
                              void* d_out, int out_size, void* d_ws, size_t ws_size,
                              hipStream_t stream) {
    const float* x  = (const float*)d_in[0];
    const float* y  = (const float*)d_in[1];
    const float* w1 = (const float*)d_in[2];
    const float* b1 = (const float*)d_in[3];
    const float* w2 = (const float*)d_in[4];
    const float* b2 = (const float*)d_in[5];
    const int* nbr  = (const int*)d_in[6];
    float* out = (float*)d_out;

    char* ws = (char*)d_ws;
    uint16_t* h2     = (uint16_t*)ws;
    uint16_t* w1t_hi = (uint16_t*)(ws + W1T_HI_OFF);
    uint16_t* w1t_lo = (uint16_t*)(ws + W1T_LO_OFF);
    uint16_t* w2t_hi = (uint16_t*)(ws + W2T_HI_OFF);
    uint16_t* w2t_lo = (uint16_t*)(ws + W2T_LO_OFF);

    const int prep_threads = TAPS * 64 * 128 + TAPS * 64 * 64 + 128;
    prep_weights<<<(prep_threads + 255) / 256, 256, 0, stream>>>(
        w1, w2, w1t_hi, w1t_lo, w2t_hi, w2t_lo, h2);

    dim3 block(256);
    dim3 grid(NPTS / 128);   // 3125
    conv1_kernel<<<grid, block, 0, stream>>>(x, y, w1t_hi, w1t_lo, b1, nbr, h2);
    conv2_kernel<<<grid, block, 0, stream>>>(h2, w2t_hi, w2t_lo, b2, nbr, out);
}